// Round 2
// baseline (281.907 us; speedup 1.0000x reference)
//
#include <hip/hip_runtime.h>

// GCN(3 layers) + MLP(4 layers), N=50000, E=800000, out = N x 8 bf16.
// NOTE: do NOT include <hip/hip_bf16.h> — breaks this harness's build
// (rounds 1-4 fell back to a stub; round 5 proved it). Manual bf16 ushort ops.
// Dtype runtime-detection: flagI (edge_index int64 vs int32), flagF (floats
// fp32 vs packed bf16) — self-detected per block via butterfly reduce.
//
// R21: layer-3 agg + GEMM3 + whole MLP fused into ONE 1024-thread kernel.
// R22: X pre-converted fp32->bf16 (xb). Gain was only 7 µs => gathers are
// NOT HBM-BW-bound (1 TB/s effective << random-line capability); they are
// latency+VALU bound.
// R23 (this round): kill the per-edge dependent chain & double MLP:
//  - bufA/bufB rows pre-scaled by dinv[row] at epilogue write => gather is
//    an unweighted sum (no per-edge dinv load, no weight FMA); AL gets
//    di*(acc + h'[node]).
//  - zero-row GN padding (rows GN of xb/bufA/bufB zeroed in prep;
//    dinv[GN]=0) => tail edges load zeros, no per-element masking.
//  - 32-edge unrolled gather: 8 rows in flight (layer 1: 4 + 4 dinv).

#define GN 50000
#define GE 800000
#define NPART 98        // partitions of 512 dst nodes
#define PSLOT 9216      // slab capacity per partition (mean 8163, +11 sigma)
#define CHK 2048        // edges per block in pass 1

typedef __attribute__((ext_vector_type(8))) short bf16x8;
typedef __attribute__((ext_vector_type(4))) float floatx4;

__device__ __forceinline__ float ar1_b2f(unsigned short h) {
    return __uint_as_float(((unsigned)h) << 16);
}
__device__ __forceinline__ unsigned short ar1_f2b(float f) {
    unsigned u = __float_as_uint(f);
    u = u + 0x7FFFu + ((u >> 16) & 1u);   // round-to-nearest-even
    return (unsigned short)(u >> 16);
}

// wave-parallel detectors (4 loads + butterfly; every wave gets the answer)
__device__ __forceinline__ int ar1_det64(const int* ei) {
    int l = (int)threadIdx.x & 63;
    int nz = 0;
#pragma unroll
    for (int k = 0; k < 4; k++)
        nz += (ei[2 * (l + 64 * k) + 1] != 0) ? 1 : 0;
#pragma unroll
    for (int o = 1; o < 64; o <<= 1)
        nz += __shfl_xor(nz, o, 64);
    return (nz < 8) ? 1 : 0;                 // 1 => int64
}
__device__ __forceinline__ int ar1_detf32(const unsigned short* xw) {
    int l = (int)threadIdx.x & 63;
    int c = 0;
#pragma unroll
    for (int k = 0; k < 4; k++) {
        unsigned short w = xw[2 * (l + 64 * k)];
        int ex = (w >> 7) & 0xFF;
        if (w == 0 || (ex >= 90 && ex <= 150)) c++;
    }
#pragma unroll
    for (int o = 1; o < 64; o <<= 1)
        c += __shfl_xor(c, o, 64);
    return (c > 200) ? 0 : 1;                // 1 => fp32
}

struct PackAll {
    const void* src[7];
    unsigned short* dst[7];
    int K[7], M[7], start[8];
};
struct SmallCvt {
    const void* src[4];   // lb1, lb2, lb3, lb4
    float* dst[4];
    int n[4];
    const void* gb[9];    // b1,g1,be1, b2,g2,be2, b3,g3,be3
    float* ss[6];         // scale1,shift1, ...
};

// merged prep (carries harness kernel name), grid = 391 + 45 + 1 + 1563 = 2000:
//  b<391: edge partition pass (self-detected is64); needs gcur pre-zeroed.
//  b<436: pack 4 MFMA B-fragments each (self-detected flagF).
//  b==436: small cvt + BN fold; zero-rows + dinv[GN]; writes flagI/flagF.
//  b>=437: X -> Xb bf16 conversion (8 elems/thread, streaming).
__global__ __launch_bounds__(256)
void Arthur1_16458314678864_kernel(PackAll pa, SmallCvt sc,
                                   const int* __restrict__ ei,
                                   const unsigned short* __restrict__ xw,
                                   int* flagI, int* flagF,
                                   int* __restrict__ gcur,
                                   unsigned int* __restrict__ pairs,
                                   unsigned short* __restrict__ xb,
                                   unsigned short* __restrict__ bufA,
                                   unsigned short* __restrict__ bufB,
                                   float* __restrict__ dinvp) {
    int b = (int)blockIdx.x;
    int tid = (int)threadIdx.x;
    if (b < 391) {
        __shared__ int cnt[NPART], base[NPART], cur[NPART];
        for (int i = tid; i < NPART; i += 256) { cnt[i] = 0; cur[i] = 0; }
        int is64 = ar1_det64(ei);
        __syncthreads();
        int e0 = b * CHK;
        unsigned pk[8]; int q[8];
#pragma unroll
        for (int k = 0; k < 8; k++) {
            int e = e0 + k * 256 + tid;
            q[k] = -1; pk[k] = 0;
            if (e < GE) {
                int s = is64 ? ei[2 * e] : ei[e];
                int d = is64 ? ei[2 * (GE + e)] : ei[GE + e];
                if ((unsigned)s < (unsigned)GN && (unsigned)d < (unsigned)GN) {
                    int qq = d >> 9;
                    q[k] = qq;
                    pk[k] = (unsigned)s | ((unsigned)(d & 511) << 17);
                    atomicAdd(&cnt[qq], 1);
                }
            }
        }
        __syncthreads();
        for (int i = tid; i < NPART; i += 256)
            base[i] = (cnt[i] > 0) ? atomicAdd(&gcur[i], cnt[i]) : 0;
        __syncthreads();
#pragma unroll
        for (int k = 0; k < 8; k++) {
            if (q[k] >= 0) {
                int r = base[q[k]] + atomicAdd(&cur[q[k]], 1);
                if (r < PSLOT) pairs[(size_t)q[k] * PSLOT + r] = pk[k];
            }
        }
    } else if (b < 436) {
        int f = ar1_detf32(xw);
        int frag_g = (b - 391) * 4 + (tid >> 6);
        if (frag_g >= 178) return;
        int w = 0;
        while (w < 6 && frag_g >= pa.start[w + 1]) w++;
        int frag = frag_g - pa.start[w];
        int K = pa.K[w], M = pa.M[w];
        int lane = tid & 63;
        int nch = K >> 5;
        int t = frag / nch, c = frag - t * nch;
        int n = t * 16 + (lane & 15);
        int k0 = c * 32 + (lane >> 4) * 8;
        unsigned short* o = pa.dst[w] + ((size_t)frag * 64 + lane) * 8;
        for (int j = 0; j < 8; j++) {
            unsigned short v = 0;
            if (n < M) {
                int idx = (k0 + j) * M + n;
                v = f ? ar1_f2b(((const float*)pa.src[w])[idx])
                      : ((const unsigned short*)pa.src[w])[idx];
            }
            o[j] = v;
        }
    } else if (b == 436) {
        int f = ar1_detf32(xw);
        int i64 = ar1_det64(ei);
        if (tid == 0) { flagI[0] = i64; flagF[0] = f; dinvp[GN] = 0.f; }
        // zero pad rows (row GN) for the zero-row gather-padding trick
        if (tid < 96) {
            bufA[(size_t)GN * 96 + tid] = 0;
            bufB[(size_t)GN * 96 + tid] = 0;
        }
        if (tid >= 96 && tid < 160) xb[(size_t)GN * 64 + (tid - 96)] = 0;
        const float C = 0.9999950000374997f;   // 1/sqrt(1+1e-5)
        for (int s = 0; s < 4; s++) {
            for (int i = tid; i < sc.n[s]; i += 256) {
                float v = f ? ((const float*)sc.src[s])[i]
                            : ar1_b2f(((const unsigned short*)sc.src[s])[i]);
                sc.dst[s][i] = v;
            }
        }
        for (int k = 0; k < 3; k++) {
            for (int i = tid; i < 96; i += 256) {
                float bb, g, be;
                if (f) {
                    bb = ((const float*)sc.gb[3 * k + 0])[i];
                    g  = ((const float*)sc.gb[3 * k + 1])[i];
                    be = ((const float*)sc.gb[3 * k + 2])[i];
                } else {
                    bb = ar1_b2f(((const unsigned short*)sc.gb[3 * k + 0])[i]);
                    g  = ar1_b2f(((const unsigned short*)sc.gb[3 * k + 1])[i]);
                    be = ar1_b2f(((const unsigned short*)sc.gb[3 * k + 2])[i]);
                }
                sc.ss[2 * k + 0][i] = C * g;
                sc.ss[2 * k + 1][i] = bb * C * g + be;
            }
        }
    } else {
        // X -> bf16 rows (one cache line per row for the layer-1 gather).
        int f = ar1_detf32(xw);
        size_t t = (size_t)(b - 437) * 256 + (size_t)tid;
        size_t i0 = t * 8;
        if (i0 < (size_t)GN * 64) {
            bf16x8 o;
            if (f) {
                const float* xf = (const float*)xw;
                floatx4 a = *((const floatx4*)(xf + i0));
                floatx4 c = *((const floatx4*)(xf + i0 + 4));
#pragma unroll
                for (int j = 0; j < 4; j++) {
                    o[j]     = (short)ar1_f2b(a[j]);
                    o[4 + j] = (short)ar1_f2b(c[j]);
                }
            } else {
                o = *((const bf16x8*)(xw + i0));
            }
            *((bf16x8*)(xb + i0)) = o;
        }
    }
}

// per-partition -> contiguous CSR slice + indeg/offs/dinv (self-scans gbase)
__global__ __launch_bounds__(256)
void ar1_csr(const unsigned int* __restrict__ pairs, const int* __restrict__ gcur,
             int* __restrict__ csr, int* __restrict__ indeg,
             int* __restrict__ offs, float* __restrict__ dinv) {
    __shared__ int ncnt[512], pre[512], cur[512], psum[16], red[256];
    int p = (int)blockIdx.x, tid = (int)threadIdx.x;
    red[tid] = (tid < p && tid < NPART) ? gcur[tid] : 0;
    __syncthreads();
    for (int o = 128; o > 0; o >>= 1) {
        if (tid < o) red[tid] += red[tid + o];
        __syncthreads();
    }
    int gbase = red[0];
    int cntE = gcur[p];
    if (cntE > PSLOT) cntE = PSLOT;
    for (int i = tid; i < 512; i += 256) ncnt[i] = 0;
    __syncthreads();
    const unsigned int* pp = pairs + (size_t)p * PSLOT;
    for (int i = tid; i < cntE; i += 256) atomicAdd(&ncnt[pp[i] >> 17], 1);
    __syncthreads();
    if (tid < 16) {
        int s = 0;
        for (int j = tid * 32; j < tid * 32 + 32; j++) { pre[j] = s; s += ncnt[j]; }
        psum[tid] = s;
    }
    __syncthreads();
    if (tid == 0) {
        int s = 0;
        for (int j = 0; j < 16; j++) { int t = psum[j]; psum[j] = s; s += t; }
    }
    __syncthreads();
    if (tid < 16)
        for (int j = tid * 32; j < tid * 32 + 32; j++) pre[j] += psum[tid];
    __syncthreads();
    for (int j = tid; j < 512; j += 256) {
        cur[j] = pre[j];
        int node = p * 512 + j;
        if (node < GN) {
            indeg[node] = ncnt[j];
            offs[node] = gbase + pre[j];
            dinv[node] = rsqrtf((float)(ncnt[j] + 1));   // +1: self loop
        }
    }
    __syncthreads();
    for (int i = tid; i < cntE; i += 256) {
        unsigned v = pp[i];
        int r = atomicAdd(&cur[v >> 17], 1);
        csr[gbase + r] = (int)(v & 0x1FFFFu);
    }
}

// ---------------- fused agg64 + GEMM1 (64->96) ------------------------------
// 1024 threads = 16 waves = 16 nodes, ONE node per wave. 32-edge unrolled
// gather: 4 row loads + 4 dinv loads in flight. Epilogue writes
// bufA[row] = dinv[row] * relu(bn(gemm)) (pre-scaled for layer 2).
__global__ __launch_bounds__(1024, 8)
void ar1_ag64g(const unsigned short* __restrict__ Xb, const int* __restrict__ offs,
               const int* __restrict__ indeg, const int* __restrict__ csr,
               const float* __restrict__ dinv,
               const unsigned short* __restrict__ Bp,
               const float* __restrict__ scale, const float* __restrict__ shift,
               unsigned short* __restrict__ C) {
    __shared__ unsigned short AL[16 * 72];
    int tid = (int)threadIdx.x, wv = tid >> 6, lane = tid & 63;
    int nb = (int)blockIdx.x * 16;
    int node = nb + wv;                 // GN = 3125*16 exactly
    int chunk = lane & 7, eslot = lane >> 3;
    float di = dinv[node];
    int off = offs[node], cnt = indeg[node];

    float acc[8];
#pragma unroll
    for (int j = 0; j < 8; j++) acc[j] = 0.f;

    for (int base = 0; base < cnt; base += 32) {
        int ss[4]; float ww[4];
#pragma unroll
        for (int k = 0; k < 4; k++) {
            int e = base + k * 8 + eslot;
            int s = (e < cnt) ? csr[off + e] : GN;   // row GN is all zeros
            ss[k] = s;
            ww[k] = dinv[s] * di;                    // dinv[GN]=0
        }
        bf16x8 hh[4];
#pragma unroll
        for (int k = 0; k < 4; k++)
            hh[k] = *((const bf16x8*)(Xb + (size_t)ss[k] * 64 + chunk * 8));
#pragma unroll
        for (int k = 0; k < 4; k++)
#pragma unroll
            for (int j = 0; j < 8; j++)
                acc[j] += ww[k] * ar1_b2f((unsigned short)hh[k][j]);
    }
#pragma unroll
    for (int j = 0; j < 8; j++) {
        acc[j] += __shfl_xor(acc[j], 8, 64);
        acc[j] += __shfl_xor(acc[j], 16, 64);
        acc[j] += __shfl_xor(acc[j], 32, 64);
    }
    if (eslot == 0) {
        bf16x8 h = *((const bf16x8*)(Xb + (size_t)node * 64 + chunk * 8));
        bf16x8 o;
#pragma unroll
        for (int j = 0; j < 8; j++)
            o[j] = (short)ar1_f2b(acc[j] + di * di * ar1_b2f((unsigned short)h[j]));
        *((bf16x8*)(AL + (size_t)wv * 72 + chunk * 8)) = o;
    }
    __syncthreads();

    if (wv < 6) {                       // GEMM: t = wv, K=64 (nch=2)
        int m = lane & 15, quad = lane >> 4, t = wv;
        floatx4 g = (floatx4){0.f, 0.f, 0.f, 0.f};
#pragma unroll
        for (int c = 0; c < 2; c++) {
            bf16x8 a = *((const bf16x8*)(AL + (size_t)m * 72 + c * 32 + quad * 8));
            bf16x8 bfr = *((const bf16x8*)(Bp + ((size_t)(t * 2 + c) * 64 + lane) * 8));
            g = __builtin_amdgcn_mfma_f32_16x16x32_bf16(a, bfr, g, 0, 0, 0);
        }
#pragma unroll
        for (int r = 0; r < 4; r++) {
            int row = nb + quad * 4 + r;
            int col = t * 16 + m;
            float v = g[r] * scale[col] + shift[col];
            C[(size_t)row * 96 + col] = ar1_f2b(dinv[row] * fmaxf(v, 0.f));
        }
    }
}

// ---------------- fused agg96 + GEMM2 (96->96) ------------------------------
// H rows are pre-scaled by dinv => gather is an unweighted sum; 32-edge
// unroll, 8 rows in flight. AL = di*(acc + H'[node]). Epilogue pre-scales.
__global__ __launch_bounds__(1024, 8)
void ar1_ag96g(const unsigned short* __restrict__ H, const int* __restrict__ offs,
               const int* __restrict__ indeg, const int* __restrict__ csr,
               const float* __restrict__ dinv,
               const unsigned short* __restrict__ Bp,
               const float* __restrict__ scale, const float* __restrict__ shift,
               unsigned short* __restrict__ C) {
    __shared__ unsigned short AL[16 * 104];
    int tid = (int)threadIdx.x, wv = tid >> 6, lane = tid & 63;
    int nb = (int)blockIdx.x * 16;
    int node = nb + wv;
    int chunk = lane % 12, eslot = lane / 12;
    float di = dinv[node];
    int off = offs[node], cnt = indeg[node];

    float acc[8];
#pragma unroll
    for (int j = 0; j < 8; j++) acc[j] = 0.f;

    if (lane < 48) {
        for (int base = 0; base < cnt; base += 32) {
            int ss[8];
#pragma unroll
            for (int k = 0; k < 8; k++) {
                int e = base + k * 4 + eslot;
                ss[k] = (e < cnt) ? csr[off + e] : GN;   // row GN all zeros
            }
            bf16x8 hh[8];
#pragma unroll
            for (int k = 0; k < 8; k++)
                hh[k] = *((const bf16x8*)(H + (size_t)ss[k] * 96 + chunk * 8));
#pragma unroll
            for (int k = 0; k < 8; k++)
#pragma unroll
                for (int j = 0; j < 8; j++)
                    acc[j] += ar1_b2f((unsigned short)hh[k][j]);
        }
    }
#pragma unroll
    for (int j = 0; j < 8; j++) {
        float a1 = __shfl(acc[j], lane + 12, 64);
        float a2 = __shfl(acc[j], lane + 24, 64);
        float a3 = __shfl(acc[j], lane + 36, 64);
        acc[j] += a1 + a2 + a3;
    }
    if (lane < 12) {
        bf16x8 hs = *((const bf16x8*)(H + (size_t)node * 96 + chunk * 8));
        bf16x8 o;
#pragma unroll
        for (int j = 0; j < 8; j++)
            o[j] = (short)ar1_f2b(di * (acc[j] + ar1_b2f((unsigned short)hs[j])));
        *((bf16x8*)(AL + (size_t)wv * 104 + chunk * 8)) = o;
    }
    __syncthreads();

    if (wv < 6) {                       // GEMM: t = wv, K=96 (nch=3)
        int m = lane & 15, quad = lane >> 4, t = wv;
        floatx4 g = (floatx4){0.f, 0.f, 0.f, 0.f};
#pragma unroll
        for (int c = 0; c < 3; c++) {
            bf16x8 a = *((const bf16x8*)(AL + (size_t)m * 104 + c * 32 + quad * 8));
            bf16x8 bfr = *((const bf16x8*)(Bp + ((size_t)(t * 3 + c) * 64 + lane) * 8));
            g = __builtin_amdgcn_mfma_f32_16x16x32_bf16(a, bfr, g, 0, 0, 0);
        }
#pragma unroll
        for (int r = 0; r < 4; r++) {
            int row = nb + quad * 4 + r;
            int col = t * 16 + m;
            float v = g[r] * scale[col] + shift[col];
            C[(size_t)row * 96 + col] = ar1_f2b(dinv[row] * fmaxf(v, 0.f));
        }
    }
}

// ---------------- fused agg96 + GEMM3 + full MLP -> d_out -------------------
// Gather identical to ag96g (pre-scaled H, unweighted sum, 32-edge unroll);
// then barriered compute phases: GEMM3 (waves 0-5), L1 (all 16), L2 (0-7),
// L3 (0-3), L4 (wave 0 -> out).
__global__ __launch_bounds__(1024, 8)
void ar1_agmlp(const unsigned short* __restrict__ H, const int* __restrict__ offs,
               const int* __restrict__ indeg, const int* __restrict__ csr,
               const float* __restrict__ dinv,
               const unsigned short* __restrict__ b2w,
               const float* __restrict__ sc3, const float* __restrict__ sh3,
               const unsigned short* __restrict__ b3,
               const unsigned short* __restrict__ b4,
               const unsigned short* __restrict__ b5,
               const unsigned short* __restrict__ b6,
               const float* __restrict__ lb0, const float* __restrict__ lb1,
               const float* __restrict__ lb2, const float* __restrict__ lb3,
               void* __restrict__ out, const int* __restrict__ f32out) {
    __shared__ unsigned short AL[16 * 104];   // aggregate rows
    __shared__ unsigned short H0[16 * 104];   // gemm3 out (96 cols)
    __shared__ unsigned short H1[16 * 264];   // 256 cols
    __shared__ unsigned short H2[16 * 136];   // 128 cols
    __shared__ unsigned short H3[16 * 72];    // 64 cols
    int tid = (int)threadIdx.x, wv = tid >> 6, lane = tid & 63;
    int nb = (int)blockIdx.x * 16;
    int node = nb + wv;
    int m = lane & 15, quad = lane >> 4;

    // ---- gather phase (one node per wave) ----
    {
        int chunk = lane % 12, eslot = lane / 12;
        float di = dinv[node];
        int off = offs[node], cnt = indeg[node];
        float acc[8];
#pragma unroll
        for (int j = 0; j < 8; j++) acc[j] = 0.f;
        if (lane < 48) {
            for (int base = 0; base < cnt; base += 32) {
                int ss[8];
#pragma unroll
                for (int k = 0; k < 8; k++) {
                    int e = base + k * 4 + eslot;
                    ss[k] = (e < cnt) ? csr[off + e] : GN;
                }
                bf16x8 hh[8];
#pragma unroll
                for (int k = 0; k < 8; k++)
                    hh[k] = *((const bf16x8*)(H + (size_t)ss[k] * 96 + chunk * 8));
#pragma unroll
                for (int k = 0; k < 8; k++)
#pragma unroll
                    for (int j = 0; j < 8; j++)
                        acc[j] += ar1_b2f((unsigned short)hh[k][j]);
            }
        }
#pragma unroll
        for (int j = 0; j < 8; j++) {
            float a1 = __shfl(acc[j], lane + 12, 64);
            float a2 = __shfl(acc[j], lane + 24, 64);
            float a3 = __shfl(acc[j], lane + 36, 64);
            acc[j] += a1 + a2 + a3;
        }
        if (lane < 12) {
            bf16x8 hs = *((const bf16x8*)(H + (size_t)node * 96 + chunk * 8));
            bf16x8 o;
#pragma unroll
            for (int j = 0; j < 8; j++)
                o[j] = (short)ar1_f2b(di * (acc[j] + ar1_b2f((unsigned short)hs[j])));
            *((bf16x8*)(AL + (size_t)wv * 104 + chunk * 8)) = o;
        }
    }
    __syncthreads();

    // ---- GEMM3: 96 -> 96, affine+ReLU (waves 0-5) ----
    if (wv < 6) {
        int t = wv;
        floatx4 g = (floatx4){0.f, 0.f, 0.f, 0.f};
#pragma unroll
        for (int c = 0; c < 3; c++) {
            bf16x8 a = *((const bf16x8*)(AL + (size_t)m * 104 + c * 32 + quad * 8));
            bf16x8 bfr = *((const bf16x8*)(b2w + ((size_t)(t * 3 + c) * 64 + lane) * 8));
            g = __builtin_amdgcn_mfma_f32_16x16x32_bf16(a, bfr, g, 0, 0, 0);
        }
#pragma unroll
        for (int r = 0; r < 4; r++) {
            int col = t * 16 + m;
            float v = g[r] * sc3[col] + sh3[col];
            H0[(quad * 4 + r) * 104 + col] = ar1_f2b(fmaxf(v, 0.f));
        }
    }
    __syncthreads();

    // ---- MLP L1: 96 -> 256 (+lb0, ReLU) (all 16 waves) ----
    {
        int t = wv;
        floatx4 g = (floatx4){0.f, 0.f, 0.f, 0.f};
#pragma unroll
        for (int c = 0; c < 3; c++) {
            bf16x8 a = *((const bf16x8*)(H0 + (size_t)m * 104 + c * 32 + quad * 8));
            bf16x8 bfr = *((const bf16x8*)(b3 + ((size_t)(t * 3 + c) * 64 + lane) * 8));
            g = __builtin_amdgcn_mfma_f32_16x16x32_bf16(a, bfr, g, 0, 0, 0);
        }
#pragma unroll
        for (int r = 0; r < 4; r++) {
            int col = t * 16 + m;
            H1[(quad * 4 + r) * 264 + col] = ar1_f2b(fmaxf(g[r] + lb0[col], 0.f));
        }
    }
    __syncthreads();

    // ---- MLP L2: 256 -> 128 (+lb1, ReLU) (waves 0-7) ----
    if (wv < 8) {
        int t = wv;
        floatx4 g = (floatx4){0.f, 0.f, 0.f, 0.f};
#pragma unroll
        for (int c = 0; c < 8; c++) {
            bf16x8 a = *((const bf16x8*)(H1 + (size_t)m * 264 + c * 32 + quad * 8));
            bf16x8 bfr = *((const bf16x8*)(b4 + ((size_t)(t * 8 + c) * 64 + lane) * 8));
            g = __builtin_amdgcn_mfma_f32_16x16x32_bf16(a, bfr, g, 0, 0, 0);
        }
#pragma unroll
        for (int r = 0; r < 4; r++) {
            int col = t * 16 + m;
            H2[(quad * 4 + r) * 136 + col] = ar1_f2b(fmaxf(g[r] + lb1[col], 0.f));
        }
    }
    __syncthreads();

    // ---- MLP L3: 128 -> 64 (+lb2, ReLU) (waves 0-3) ----
    if (wv < 4) {
        int t = wv;
        floatx4 g = (floatx4){0.f, 0.f, 0.f, 0.f};
#pragma unroll
        for (int c = 0; c < 4; c++) {
            bf16x8 a = *((const bf16x8*)(H2 + (size_t)m * 136 + c * 32 + quad * 8));
            bf16x8 bfr = *((const bf16x8*)(b5 + ((size_t)(t * 4 + c) * 64 + lane) * 8));
            g = __builtin_amdgcn_mfma_f32_16x16x32_bf16(a, bfr, g, 0, 0, 0);
        }
#pragma unroll
        for (int r = 0; r < 4; r++) {
            int col = t * 16 + m;
            H3[(quad * 4 + r) * 72 + col] = ar1_f2b(fmaxf(g[r] + lb2[col], 0.f));
        }
    }
    __syncthreads();

    // ---- MLP L4: 64 -> 8 (+lb3) (wave 0 -> out) ----
    if (wv == 0) {
        floatx4 g = (floatx4){0.f, 0.f, 0.f, 0.f};
#pragma unroll
        for (int c = 0; c < 2; c++) {
            bf16x8 a = *((const bf16x8*)(H3 + (size_t)m * 72 + c * 32 + quad * 8));
            bf16x8 bfr = *((const bf16x8*)(b6 + ((size_t)c * 64 + lane) * 8));
            g = __builtin_amdgcn_mfma_f32_16x16x32_bf16(a, bfr, g, 0, 0, 0);
        }
        int wf32 = f32out[0];
#pragma unroll
        for (int r = 0; r < 4; r++) {
            int row = nb + quad * 4 + r;
            if (m < 8) {
                float v = g[r] + lb3[m];
                if (wf32) ((float*)out)[(size_t)row * 8 + m] = v;
                else ((unsigned short*)out)[(size_t)row * 8 + m] = ar1_f2b(v);
            }
        }
    }
}

extern "C" void kernel_launch(void* const* d_in, const int* in_sizes, int n_in,
                              void* d_out, int out_size, void* d_ws, size_t ws_size,
                              hipStream_t stream) {
    (void)in_sizes; (void)n_in; (void)out_size;

    // workspace layout (+1 zero row on xb/bufA/bufB; dinv padded for [GN])
    char* p = (char*)d_ws;
    unsigned short* bufA = (unsigned short*)p; p += (size_t)(GN + 1) * 96 * 2;
    unsigned short* bufB = (unsigned short*)p; p += (size_t)(GN + 1) * 96 * 2;
    unsigned short* xb   = (unsigned short*)p; p += (size_t)(GN + 1) * 64 * 2;
    unsigned int* pairs = (unsigned int*)p; p += (size_t)NPART * PSLOT * 4; // 3.6 MB
    int* indeg  = (int*)p;    p += (size_t)GN * 4;
    int* offs   = (int*)p;    p += (size_t)GN * 4;
    float* dinv = (float*)p;  p += (size_t)GN * 4 + 64;
    int* csr    = (int*)p;    p += (size_t)GE * 4;
    int* gcur   = (int*)p;    p += 1024;
    int* flagI  = (int*)p;    p += 1024;
    int* flagF  = (int*)p;    p += 1024;
    unsigned short* bpArena = (unsigned short*)p; p += 91136 * 2;  // packed W
    float* fArena = (float*)p; p += 2048 * 4;                      // small fp32
    size_t need = (size_t)(p - (char*)d_ws);
    if (ws_size < need) {
        hipMemsetAsync(d_out, 0x41, (size_t)GN * 8 * 2, stream);  // marker 12.06
        return;
    }

    // packed-weight arena offsets (shorts): w1,w2,w3,lw1,lw2,lw3,lw4
    unsigned short* bp[7];
    int bpn[7] = {6144, 9216, 9216, 24576, 32768, 8192, 1024};
    {
        unsigned short* q = bpArena;
        for (int i = 0; i < 7; i++) { bp[i] = q; q += bpn[i]; }
    }

    // small fp32 arena: lb1(256),lb2(128),lb3(64),lb4(8), 6 x 96 scale/shift
    float* lb[4]; float* ss[6];
    {
        float* q = fArena;
        int ln[4] = {256, 128, 64, 8};
        for (int i = 0; i < 4; i++) { lb[i] = q; q += ln[i]; }
        for (int i = 0; i < 6; i++) { ss[i] = q; q += 96; }
    }

    const int* ei = (const int*)d_in[1];
    const unsigned short* xw = (const unsigned short*)d_in[0];

    // graph build + weight prep + X->bf16: memset, merged kernel, csr
    hipMemsetAsync(gcur, 0, NPART * 4, stream);
    {
        PackAll pa;
        int wsrc[7] = {2, 6, 10, 14, 16, 18, 20};
        int Ks[7] = {64, 96, 96, 96, 256, 128, 64};
        int Ms[7] = {96, 96, 96, 256, 128, 64, 8};
        int cum = 0;
        for (int i = 0; i < 7; i++) {
            pa.src[i] = d_in[wsrc[i]]; pa.dst[i] = bp[i];
            pa.K[i] = Ks[i]; pa.M[i] = Ms[i];
            pa.start[i] = cum;
            cum += (Ms[i] + 15) / 16 * (Ks[i] / 32);
        }
        pa.start[7] = cum;   // 178
        SmallCvt sc;
        int lsrc[4] = {15, 17, 19, 21};
        int ln[4] = {256, 128, 64, 8};
        for (int i = 0; i < 4; i++) { sc.src[i] = d_in[lsrc[i]]; sc.dst[i] = lb[i]; sc.n[i] = ln[i]; }
        int gsrc[9] = {3, 4, 5, 7, 8, 9, 11, 12, 13};
        for (int i = 0; i < 9; i++) sc.gb[i] = d_in[gsrc[i]];
        for (int i = 0; i < 6; i++) sc.ss[i] = ss[i];
        Arthur1_16458314678864_kernel<<<2000, 256, 0, stream>>>(
            pa, sc, ei, xw, flagI, flagF, gcur, pairs, xb, bufA, bufB, dinv);
    }
    ar1_csr<<<NPART, 256, 0, stream>>>(pairs, gcur, csr, indeg, offs, dinv);

    const int FB = GN / 16;           // 3125 (fused kernels, 1024 thr)

    // GCN layers 1,2 fused agg+GEMM; layer 3 + GEMM3 + MLP in one kernel
    ar1_ag64g<<<FB, 1024, 0, stream>>>(xb, offs, indeg, csr, dinv,
                                       bp[0], ss[0], ss[1], bufA);
    ar1_ag96g<<<FB, 1024, 0, stream>>>(bufA, offs, indeg, csr, dinv,
                                       bp[1], ss[2], ss[3], bufB);
    ar1_agmlp<<<FB, 1024, 0, stream>>>(bufB, offs, indeg, csr, dinv,
                                       bp[2], ss[4], ss[5],
                                       bp[3], bp[4], bp[5], bp[6],
                                       lb[0], lb[1], lb[2], lb[3], d_out, flagF);
}

// Round 3
// 277.668 us; speedup vs baseline: 1.0153x; 1.0153x over previous
//
#include <hip/hip_runtime.h>

// GCN(3 layers) + MLP(4 layers), N=50000, E=800000, out = N x 8 bf16.
// NOTE: do NOT include <hip/hip_bf16.h> — breaks this harness's build
// (rounds 1-4 fell back to a stub; round 5 proved it). Manual bf16 ushort ops.
// Dtype runtime-detection: flagI (edge_index int64 vs int32), flagF (floats
// fp32 vs packed bf16) — self-detected per block via butterfly reduce.
//
// R22: X pre-converted fp32->bf16 (xb): gathers are latency-bound, not BW.
// R23: pre-scaled rows + 32-edge unroll => REGRESSED via scratch spills
//      (launch_bounds(1024,8) pins 32 VGPR; hh[8]+acc[8] overflows; agmlp
//      WRITE_SIZE 1.5->38.8 MB = spill traffic) + 119% tail padding.
// R24 (this round): keep the algebra, restore the register footprint:
//  - 16-edge chunks (4 rows in flight for 96-wide, 2 for 64-wide) — the
//    proven no-spill footprint, now minus per-edge dinv load & weight FMA.
//  - xb rows pre-scaled by dinv in ar1_csr (ncnt already in LDS) => all 3
//    gathers are plain unweighted sums; AL = di*(acc + h'[node]).

#define GN 50000
#define GE 800000
#define NPART 98        // partitions of 512 dst nodes
#define PSLOT 9216      // slab capacity per partition (mean 8163, +11 sigma)
#define CHK 2048        // edges per block in pass 1

typedef __attribute__((ext_vector_type(8))) short bf16x8;
typedef __attribute__((ext_vector_type(4))) float floatx4;

__device__ __forceinline__ float ar1_b2f(unsigned short h) {
    return __uint_as_float(((unsigned)h) << 16);
}
__device__ __forceinline__ unsigned short ar1_f2b(float f) {
    unsigned u = __float_as_uint(f);
    u = u + 0x7FFFu + ((u >> 16) & 1u);   // round-to-nearest-even
    return (unsigned short)(u >> 16);
}

// wave-parallel detectors (4 loads + butterfly; every wave gets the answer)
__device__ __forceinline__ int ar1_det64(const int* ei) {
    int l = (int)threadIdx.x & 63;
    int nz = 0;
#pragma unroll
    for (int k = 0; k < 4; k++)
        nz += (ei[2 * (l + 64 * k) + 1] != 0) ? 1 : 0;
#pragma unroll
    for (int o = 1; o < 64; o <<= 1)
        nz += __shfl_xor(nz, o, 64);
    return (nz < 8) ? 1 : 0;                 // 1 => int64
}
__device__ __forceinline__ int ar1_detf32(const unsigned short* xw) {
    int l = (int)threadIdx.x & 63;
    int c = 0;
#pragma unroll
    for (int k = 0; k < 4; k++) {
        unsigned short w = xw[2 * (l + 64 * k)];
        int ex = (w >> 7) & 0xFF;
        if (w == 0 || (ex >= 90 && ex <= 150)) c++;
    }
#pragma unroll
    for (int o = 1; o < 64; o <<= 1)
        c += __shfl_xor(c, o, 64);
    return (c > 200) ? 0 : 1;                // 1 => fp32
}

struct PackAll {
    const void* src[7];
    unsigned short* dst[7];
    int K[7], M[7], start[8];
};
struct SmallCvt {
    const void* src[4];   // lb1, lb2, lb3, lb4
    float* dst[4];
    int n[4];
    const void* gb[9];    // b1,g1,be1, b2,g2,be2, b3,g3,be3
    float* ss[6];         // scale1,shift1, ...
};

// merged prep (carries harness kernel name), grid = 391 + 45 + 1 + 1563 = 2000:
//  b<391: edge partition pass (self-detected is64); needs gcur pre-zeroed.
//  b<436: pack 4 MFMA B-fragments each (self-detected flagF).
//  b==436: small cvt + BN fold; zero-rows + dinv[GN]; writes flagI/flagF.
//  b>=437: X -> Xb bf16 conversion (8 elems/thread, streaming).
__global__ __launch_bounds__(256)
void Arthur1_16458314678864_kernel(PackAll pa, SmallCvt sc,
                                   const int* __restrict__ ei,
                                   const unsigned short* __restrict__ xw,
                                   int* flagI, int* flagF,
                                   int* __restrict__ gcur,
                                   unsigned int* __restrict__ pairs,
                                   unsigned short* __restrict__ xb,
                                   unsigned short* __restrict__ bufA,
                                   unsigned short* __restrict__ bufB,
                                   float* __restrict__ dinvp) {
    int b = (int)blockIdx.x;
    int tid = (int)threadIdx.x;
    if (b < 391) {
        __shared__ int cnt[NPART], base[NPART], cur[NPART];
        for (int i = tid; i < NPART; i += 256) { cnt[i] = 0; cur[i] = 0; }
        int is64 = ar1_det64(ei);
        __syncthreads();
        int e0 = b * CHK;
        unsigned pk[8]; int q[8];
#pragma unroll
        for (int k = 0; k < 8; k++) {
            int e = e0 + k * 256 + tid;
            q[k] = -1; pk[k] = 0;
            if (e < GE) {
                int s = is64 ? ei[2 * e] : ei[e];
                int d = is64 ? ei[2 * (GE + e)] : ei[GE + e];
                if ((unsigned)s < (unsigned)GN && (unsigned)d < (unsigned)GN) {
                    int qq = d >> 9;
                    q[k] = qq;
                    pk[k] = (unsigned)s | ((unsigned)(d & 511) << 17);
                    atomicAdd(&cnt[qq], 1);
                }
            }
        }
        __syncthreads();
        for (int i = tid; i < NPART; i += 256)
            base[i] = (cnt[i] > 0) ? atomicAdd(&gcur[i], cnt[i]) : 0;
        __syncthreads();
#pragma unroll
        for (int k = 0; k < 8; k++) {
            if (q[k] >= 0) {
                int r = base[q[k]] + atomicAdd(&cur[q[k]], 1);
                if (r < PSLOT) pairs[(size_t)q[k] * PSLOT + r] = pk[k];
            }
        }
    } else if (b < 436) {
        int f = ar1_detf32(xw);
        int frag_g = (b - 391) * 4 + (tid >> 6);
        if (frag_g >= 178) return;
        int w = 0;
        while (w < 6 && frag_g >= pa.start[w + 1]) w++;
        int frag = frag_g - pa.start[w];
        int K = pa.K[w], M = pa.M[w];
        int lane = tid & 63;
        int nch = K >> 5;
        int t = frag / nch, c = frag - t * nch;
        int n = t * 16 + (lane & 15);
        int k0 = c * 32 + (lane >> 4) * 8;
        unsigned short* o = pa.dst[w] + ((size_t)frag * 64 + lane) * 8;
        for (int j = 0; j < 8; j++) {
            unsigned short v = 0;
            if (n < M) {
                int idx = (k0 + j) * M + n;
                v = f ? ar1_f2b(((const float*)pa.src[w])[idx])
                      : ((const unsigned short*)pa.src[w])[idx];
            }
            o[j] = v;
        }
    } else if (b == 436) {
        int f = ar1_detf32(xw);
        int i64 = ar1_det64(ei);
        if (tid == 0) { flagI[0] = i64; flagF[0] = f; dinvp[GN] = 0.f; }
        // zero pad rows (row GN) for the zero-row gather-padding trick
        if (tid < 96) {
            bufA[(size_t)GN * 96 + tid] = 0;
            bufB[(size_t)GN * 96 + tid] = 0;
        }
        if (tid >= 96 && tid < 160) xb[(size_t)GN * 64 + (tid - 96)] = 0;
        const float C = 0.9999950000374997f;   // 1/sqrt(1+1e-5)
        for (int s = 0; s < 4; s++) {
            for (int i = tid; i < sc.n[s]; i += 256) {
                float v = f ? ((const float*)sc.src[s])[i]
                            : ar1_b2f(((const unsigned short*)sc.src[s])[i]);
                sc.dst[s][i] = v;
            }
        }
        for (int k = 0; k < 3; k++) {
            for (int i = tid; i < 96; i += 256) {
                float bb, g, be;
                if (f) {
                    bb = ((const float*)sc.gb[3 * k + 0])[i];
                    g  = ((const float*)sc.gb[3 * k + 1])[i];
                    be = ((const float*)sc.gb[3 * k + 2])[i];
                } else {
                    bb = ar1_b2f(((const unsigned short*)sc.gb[3 * k + 0])[i]);
                    g  = ar1_b2f(((const unsigned short*)sc.gb[3 * k + 1])[i]);
                    be = ar1_b2f(((const unsigned short*)sc.gb[3 * k + 2])[i]);
                }
                sc.ss[2 * k + 0][i] = C * g;
                sc.ss[2 * k + 1][i] = bb * C * g + be;
            }
        }
    } else {
        // X -> bf16 rows (one cache line per row for the layer-1 gather).
        // (dinv scaling is applied later by ar1_csr once degrees are known.)
        int f = ar1_detf32(xw);
        size_t t = (size_t)(b - 437) * 256 + (size_t)tid;
        size_t i0 = t * 8;
        if (i0 < (size_t)GN * 64) {
            bf16x8 o;
            if (f) {
                const float* xf = (const float*)xw;
                floatx4 a = *((const floatx4*)(xf + i0));
                floatx4 c = *((const floatx4*)(xf + i0 + 4));
#pragma unroll
                for (int j = 0; j < 4; j++) {
                    o[j]     = (short)ar1_f2b(a[j]);
                    o[4 + j] = (short)ar1_f2b(c[j]);
                }
            } else {
                o = *((const bf16x8*)(xw + i0));
            }
            *((bf16x8*)(xb + i0)) = o;
        }
    }
}

// per-partition -> contiguous CSR slice + indeg/offs/dinv (self-scans gbase)
// + scales this partition's xb rows by dinv (so the layer-1 gather is an
// unweighted sum, same as layers 2/3).
__global__ __launch_bounds__(256)
void ar1_csr(const unsigned int* __restrict__ pairs, const int* __restrict__ gcur,
             int* __restrict__ csr, int* __restrict__ indeg,
             int* __restrict__ offs, float* __restrict__ dinv,
             unsigned short* __restrict__ xb) {
    __shared__ int ncnt[512], pre[512], cur[512], psum[16], red[256];
    int p = (int)blockIdx.x, tid = (int)threadIdx.x;
    red[tid] = (tid < p && tid < NPART) ? gcur[tid] : 0;
    __syncthreads();
    for (int o = 128; o > 0; o >>= 1) {
        if (tid < o) red[tid] += red[tid + o];
        __syncthreads();
    }
    int gbase = red[0];
    int cntE = gcur[p];
    if (cntE > PSLOT) cntE = PSLOT;
    for (int i = tid; i < 512; i += 256) ncnt[i] = 0;
    __syncthreads();
    const unsigned int* pp = pairs + (size_t)p * PSLOT;
    for (int i = tid; i < cntE; i += 256) atomicAdd(&ncnt[pp[i] >> 17], 1);
    __syncthreads();
    if (tid < 16) {
        int s = 0;
        for (int j = tid * 32; j < tid * 32 + 32; j++) { pre[j] = s; s += ncnt[j]; }
        psum[tid] = s;
    }
    __syncthreads();
    if (tid == 0) {
        int s = 0;
        for (int j = 0; j < 16; j++) { int t = psum[j]; psum[j] = s; s += t; }
    }
    __syncthreads();
    if (tid < 16)
        for (int j = tid * 32; j < tid * 32 + 32; j++) pre[j] += psum[tid];
    __syncthreads();
    for (int j = tid; j < 512; j += 256) {
        cur[j] = pre[j];
        int node = p * 512 + j;
        if (node < GN) {
            indeg[node] = ncnt[j];
            offs[node] = gbase + pre[j];
            dinv[node] = rsqrtf((float)(ncnt[j] + 1));   // +1: self loop
        }
    }
    __syncthreads();
    for (int i = tid; i < cntE; i += 256) {
        unsigned v = pp[i];
        int r = atomicAdd(&cur[v >> 17], 1);
        csr[gbase + r] = (int)(v & 0x1FFFFu);
    }
    // scale this partition's xb rows by dinv (ncnt stable in LDS)
    for (int i = tid; i < 512 * 8; i += 256) {
        int j = i >> 3, c = i & 7;
        int node = p * 512 + j;
        if (node < GN) {
            float sc = rsqrtf((float)(ncnt[j] + 1));
            bf16x8 v = *((bf16x8*)(xb + (size_t)node * 64 + c * 8));
#pragma unroll
            for (int jj = 0; jj < 8; jj++)
                v[jj] = (short)ar1_f2b(sc * ar1_b2f((unsigned short)v[jj]));
            *((bf16x8*)(xb + (size_t)node * 64 + c * 8)) = v;
        }
    }
}

// ---------------- fused agg64 + GEMM1 (64->96) ------------------------------
// 1024 threads = 16 waves = 16 nodes, ONE node per wave. Xb rows are
// pre-scaled by dinv => unweighted sum; 16-edge chunk, 2 rows in flight.
// Epilogue writes bufA[row] = dinv[row] * relu(bn(gemm)).
__global__ __launch_bounds__(1024, 8)
void ar1_ag64g(const unsigned short* __restrict__ Xb, const int* __restrict__ offs,
               const int* __restrict__ indeg, const int* __restrict__ csr,
               const float* __restrict__ dinv,
               const unsigned short* __restrict__ Bp,
               const float* __restrict__ scale, const float* __restrict__ shift,
               unsigned short* __restrict__ C) {
    __shared__ unsigned short AL[16 * 72];
    int tid = (int)threadIdx.x, wv = tid >> 6, lane = tid & 63;
    int nb = (int)blockIdx.x * 16;
    int node = nb + wv;                 // GN = 3125*16 exactly
    int chunk = lane & 7, eslot = lane >> 3;
    float di = dinv[node];
    int off = offs[node], cnt = indeg[node];

    float acc[8];
#pragma unroll
    for (int j = 0; j < 8; j++) acc[j] = 0.f;

    for (int base = 0; base < cnt; base += 16) {
        int ss[2];
#pragma unroll
        for (int k = 0; k < 2; k++) {
            int e = base + k * 8 + eslot;
            ss[k] = (e < cnt) ? csr[off + e] : GN;   // row GN is all zeros
        }
        bf16x8 hh[2];
#pragma unroll
        for (int k = 0; k < 2; k++)
            hh[k] = *((const bf16x8*)(Xb + (size_t)ss[k] * 64 + chunk * 8));
#pragma unroll
        for (int k = 0; k < 2; k++)
#pragma unroll
            for (int j = 0; j < 8; j++)
                acc[j] += ar1_b2f((unsigned short)hh[k][j]);
    }
#pragma unroll
    for (int j = 0; j < 8; j++) {
        acc[j] += __shfl_xor(acc[j], 8, 64);
        acc[j] += __shfl_xor(acc[j], 16, 64);
        acc[j] += __shfl_xor(acc[j], 32, 64);
    }
    if (eslot == 0) {
        bf16x8 h = *((const bf16x8*)(Xb + (size_t)node * 64 + chunk * 8));
        bf16x8 o;
#pragma unroll
        for (int j = 0; j < 8; j++)
            o[j] = (short)ar1_f2b(di * (acc[j] + ar1_b2f((unsigned short)h[j])));
        *((bf16x8*)(AL + (size_t)wv * 72 + chunk * 8)) = o;
    }
    __syncthreads();

    if (wv < 6) {                       // GEMM: t = wv, K=64 (nch=2)
        int m = lane & 15, quad = lane >> 4, t = wv;
        floatx4 g = (floatx4){0.f, 0.f, 0.f, 0.f};
#pragma unroll
        for (int c = 0; c < 2; c++) {
            bf16x8 a = *((const bf16x8*)(AL + (size_t)m * 72 + c * 32 + quad * 8));
            bf16x8 bfr = *((const bf16x8*)(Bp + ((size_t)(t * 2 + c) * 64 + lane) * 8));
            g = __builtin_amdgcn_mfma_f32_16x16x32_bf16(a, bfr, g, 0, 0, 0);
        }
#pragma unroll
        for (int r = 0; r < 4; r++) {
            int row = nb + quad * 4 + r;
            int col = t * 16 + m;
            float v = g[r] * scale[col] + shift[col];
            C[(size_t)row * 96 + col] = ar1_f2b(dinv[row] * fmaxf(v, 0.f));
        }
    }
}

// ---------------- fused agg96 + GEMM2 (96->96) ------------------------------
// H rows pre-scaled by dinv => unweighted sum; 16-edge chunk, 4 rows in
// flight. AL = di*(acc + H'[node]). Epilogue pre-scales for next layer.
__global__ __launch_bounds__(1024, 8)
void ar1_ag96g(const unsigned short* __restrict__ H, const int* __restrict__ offs,
               const int* __restrict__ indeg, const int* __restrict__ csr,
               const float* __restrict__ dinv,
               const unsigned short* __restrict__ Bp,
               const float* __restrict__ scale, const float* __restrict__ shift,
               unsigned short* __restrict__ C) {
    __shared__ unsigned short AL[16 * 104];
    int tid = (int)threadIdx.x, wv = tid >> 6, lane = tid & 63;
    int nb = (int)blockIdx.x * 16;
    int node = nb + wv;
    int chunk = lane % 12, eslot = lane / 12;
    float di = dinv[node];
    int off = offs[node], cnt = indeg[node];

    float acc[8];
#pragma unroll
    for (int j = 0; j < 8; j++) acc[j] = 0.f;

    if (lane < 48) {
        for (int base = 0; base < cnt; base += 16) {
            int ss[4];
#pragma unroll
            for (int k = 0; k < 4; k++) {
                int e = base + k * 4 + eslot;
                ss[k] = (e < cnt) ? csr[off + e] : GN;   // row GN all zeros
            }
            bf16x8 hh[4];
#pragma unroll
            for (int k = 0; k < 4; k++)
                hh[k] = *((const bf16x8*)(H + (size_t)ss[k] * 96 + chunk * 8));
#pragma unroll
            for (int k = 0; k < 4; k++)
#pragma unroll
                for (int j = 0; j < 8; j++)
                    acc[j] += ar1_b2f((unsigned short)hh[k][j]);
        }
    }
#pragma unroll
    for (int j = 0; j < 8; j++) {
        float a1 = __shfl(acc[j], lane + 12, 64);
        float a2 = __shfl(acc[j], lane + 24, 64);
        float a3 = __shfl(acc[j], lane + 36, 64);
        acc[j] += a1 + a2 + a3;
    }
    if (lane < 12) {
        bf16x8 hs = *((const bf16x8*)(H + (size_t)node * 96 + chunk * 8));
        bf16x8 o;
#pragma unroll
        for (int j = 0; j < 8; j++)
            o[j] = (short)ar1_f2b(di * (acc[j] + ar1_b2f((unsigned short)hs[j])));
        *((bf16x8*)(AL + (size_t)wv * 104 + chunk * 8)) = o;
    }
    __syncthreads();

    if (wv < 6) {                       // GEMM: t = wv, K=96 (nch=3)
        int m = lane & 15, quad = lane >> 4, t = wv;
        floatx4 g = (floatx4){0.f, 0.f, 0.f, 0.f};
#pragma unroll
        for (int c = 0; c < 3; c++) {
            bf16x8 a = *((const bf16x8*)(AL + (size_t)m * 104 + c * 32 + quad * 8));
            bf16x8 bfr = *((const bf16x8*)(Bp + ((size_t)(t * 3 + c) * 64 + lane) * 8));
            g = __builtin_amdgcn_mfma_f32_16x16x32_bf16(a, bfr, g, 0, 0, 0);
        }
#pragma unroll
        for (int r = 0; r < 4; r++) {
            int row = nb + quad * 4 + r;
            int col = t * 16 + m;
            float v = g[r] * scale[col] + shift[col];
            C[(size_t)row * 96 + col] = ar1_f2b(dinv[row] * fmaxf(v, 0.f));
        }
    }
}

// ---------------- fused agg96 + GEMM3 + full MLP -> d_out -------------------
// Gather identical to ag96g; then barriered compute phases: GEMM3 (waves
// 0-5), L1 (all 16), L2 (0-7), L3 (0-3), L4 (wave 0 -> out).
__global__ __launch_bounds__(1024, 8)
void ar1_agmlp(const unsigned short* __restrict__ H, const int* __restrict__ offs,
               const int* __restrict__ indeg, const int* __restrict__ csr,
               const float* __restrict__ dinv,
               const unsigned short* __restrict__ b2w,
               const float* __restrict__ sc3, const float* __restrict__ sh3,
               const unsigned short* __restrict__ b3,
               const unsigned short* __restrict__ b4,
               const unsigned short* __restrict__ b5,
               const unsigned short* __restrict__ b6,
               const float* __restrict__ lb0, const float* __restrict__ lb1,
               const float* __restrict__ lb2, const float* __restrict__ lb3,
               void* __restrict__ out, const int* __restrict__ f32out) {
    __shared__ unsigned short AL[16 * 104];   // aggregate rows
    __shared__ unsigned short H0[16 * 104];   // gemm3 out (96 cols)
    __shared__ unsigned short H1[16 * 264];   // 256 cols
    __shared__ unsigned short H2[16 * 136];   // 128 cols
    __shared__ unsigned short H3[16 * 72];    // 64 cols
    int tid = (int)threadIdx.x, wv = tid >> 6, lane = tid & 63;
    int nb = (int)blockIdx.x * 16;
    int node = nb + wv;
    int m = lane & 15, quad = lane >> 4;

    // ---- gather phase (one node per wave) ----
    {
        int chunk = lane % 12, eslot = lane / 12;
        float di = dinv[node];
        int off = offs[node], cnt = indeg[node];
        float acc[8];
#pragma unroll
        for (int j = 0; j < 8; j++) acc[j] = 0.f;
        if (lane < 48) {
            for (int base = 0; base < cnt; base += 16) {
                int ss[4];
#pragma unroll
                for (int k = 0; k < 4; k++) {
                    int e = base + k * 4 + eslot;
                    ss[k] = (e < cnt) ? csr[off + e] : GN;
                }
                bf16x8 hh[4];
#pragma unroll
                for (int k = 0; k < 4; k++)
                    hh[k] = *((const bf16x8*)(H + (size_t)ss[k] * 96 + chunk * 8));
#pragma unroll
                for (int k = 0; k < 4; k++)
#pragma unroll
                    for (int j = 0; j < 8; j++)
                        acc[j] += ar1_b2f((unsigned short)hh[k][j]);
            }
        }
#pragma unroll
        for (int j = 0; j < 8; j++) {
            float a1 = __shfl(acc[j], lane + 12, 64);
            float a2 = __shfl(acc[j], lane + 24, 64);
            float a3 = __shfl(acc[j], lane + 36, 64);
            acc[j] += a1 + a2 + a3;
        }
        if (lane < 12) {
            bf16x8 hs = *((const bf16x8*)(H + (size_t)node * 96 + chunk * 8));
            bf16x8 o;
#pragma unroll
            for (int j = 0; j < 8; j++)
                o[j] = (short)ar1_f2b(di * (acc[j] + ar1_b2f((unsigned short)hs[j])));
            *((bf16x8*)(AL + (size_t)wv * 104 + chunk * 8)) = o;
        }
    }
    __syncthreads();

    // ---- GEMM3: 96 -> 96, affine+ReLU (waves 0-5) ----
    if (wv < 6) {
        int t = wv;
        floatx4 g = (floatx4){0.f, 0.f, 0.f, 0.f};
#pragma unroll
        for (int c = 0; c < 3; c++) {
            bf16x8 a = *((const bf16x8*)(AL + (size_t)m * 104 + c * 32 + quad * 8));
            bf16x8 bfr = *((const bf16x8*)(b2w + ((size_t)(t * 3 + c) * 64 + lane) * 8));
            g = __builtin_amdgcn_mfma_f32_16x16x32_bf16(a, bfr, g, 0, 0, 0);
        }
#pragma unroll
        for (int r = 0; r < 4; r++) {
            int col = t * 16 + m;
            float v = g[r] * sc3[col] + sh3[col];
            H0[(quad * 4 + r) * 104 + col] = ar1_f2b(fmaxf(v, 0.f));
        }
    }
    __syncthreads();

    // ---- MLP L1: 96 -> 256 (+lb0, ReLU) (all 16 waves) ----
    {
        int t = wv;
        floatx4 g = (floatx4){0.f, 0.f, 0.f, 0.f};
#pragma unroll
        for (int c = 0; c < 3; c++) {
            bf16x8 a = *((const bf16x8*)(H0 + (size_t)m * 104 + c * 32 + quad * 8));
            bf16x8 bfr = *((const bf16x8*)(b3 + ((size_t)(t * 3 + c) * 64 + lane) * 8));
            g = __builtin_amdgcn_mfma_f32_16x16x32_bf16(a, bfr, g, 0, 0, 0);
        }
#pragma unroll
        for (int r = 0; r < 4; r++) {
            int col = t * 16 + m;
            H1[(quad * 4 + r) * 264 + col] = ar1_f2b(fmaxf(g[r] + lb0[col], 0.f));
        }
    }
    __syncthreads();

    // ---- MLP L2: 256 -> 128 (+lb1, ReLU) (waves 0-7) ----
    if (wv < 8) {
        int t = wv;
        floatx4 g = (floatx4){0.f, 0.f, 0.f, 0.f};
#pragma unroll
        for (int c = 0; c < 8; c++) {
            bf16x8 a = *((const bf16x8*)(H1 + (size_t)m * 264 + c * 32 + quad * 8));
            bf16x8 bfr = *((const bf16x8*)(b4 + ((size_t)(t * 8 + c) * 64 + lane) * 8));
            g = __builtin_amdgcn_mfma_f32_16x16x32_bf16(a, bfr, g, 0, 0, 0);
        }
#pragma unroll
        for (int r = 0; r < 4; r++) {
            int col = t * 16 + m;
            H2[(quad * 4 + r) * 136 + col] = ar1_f2b(fmaxf(g[r] + lb1[col], 0.f));
        }
    }
    __syncthreads();

    // ---- MLP L3: 128 -> 64 (+lb2, ReLU) (waves 0-3) ----
    if (wv < 4) {
        int t = wv;
        floatx4 g = (floatx4){0.f, 0.f, 0.f, 0.f};
#pragma unroll
        for (int c = 0; c < 4; c++) {
            bf16x8 a = *((const bf16x8*)(H2 + (size_t)m * 136 + c * 32 + quad * 8));
            bf16x8 bfr = *((const bf16x8*)(b5 + ((size_t)(t * 4 + c) * 64 + lane) * 8));
            g = __builtin_amdgcn_mfma_f32_16x16x32_bf16(a, bfr, g, 0, 0, 0);
        }
#pragma unroll
        for (int r = 0; r < 4; r++) {
            int col = t * 16 + m;
            H3[(quad * 4 + r) * 72 + col] = ar1_f2b(fmaxf(g[r] + lb2[col], 0.f));
        }
    }
    __syncthreads();

    // ---- MLP L4: 64 -> 8 (+lb3) (wave 0 -> out) ----
    if (wv == 0) {
        floatx4 g = (floatx4){0.f, 0.f, 0.f, 0.f};
#pragma unroll
        for (int c = 0; c < 2; c++) {
            bf16x8 a = *((const bf16x8*)(H3 + (size_t)m * 72 + c * 32 + quad * 8));
            bf16x8 bfr = *((const bf16x8*)(b6 + ((size_t)c * 64 + lane) * 8));
            g = __builtin_amdgcn_mfma_f32_16x16x32_bf16(a, bfr, g, 0, 0, 0);
        }
        int wf32 = f32out[0];
#pragma unroll
        for (int r = 0; r < 4; r++) {
            int row = nb + quad * 4 + r;
            if (m < 8) {
                float v = g[r] + lb3[m];
                if (wf32) ((float*)out)[(size_t)row * 8 + m] = v;
                else ((unsigned short*)out)[(size_t)row * 8 + m] = ar1_f2b(v);
            }
        }
    }
}

extern "C" void kernel_launch(void* const* d_in, const int* in_sizes, int n_in,
                              void* d_out, int out_size, void* d_ws, size_t ws_size,
                              hipStream_t stream) {
    (void)in_sizes; (void)n_in; (void)out_size;

    // workspace layout (+1 zero row on xb/bufA/bufB; dinv padded for [GN])
    char* p = (char*)d_ws;
    unsigned short* bufA = (unsigned short*)p; p += (size_t)(GN + 1) * 96 * 2;
    unsigned short* bufB = (unsigned short*)p; p += (size_t)(GN + 1) * 96 * 2;
    unsigned short* xb   = (unsigned short*)p; p += (size_t)(GN + 1) * 64 * 2;
    unsigned int* pairs = (unsigned int*)p; p += (size_t)NPART * PSLOT * 4; // 3.6 MB
    int* indeg  = (int*)p;    p += (size_t)GN * 4;
    int* offs   = (int*)p;    p += (size_t)GN * 4;
    float* dinv = (float*)p;  p += (size_t)GN * 4 + 64;
    int* csr    = (int*)p;    p += (size_t)GE * 4;
    int* gcur   = (int*)p;    p += 1024;
    int* flagI  = (int*)p;    p += 1024;
    int* flagF  = (int*)p;    p += 1024;
    unsigned short* bpArena = (unsigned short*)p; p += 91136 * 2;  // packed W
    float* fArena = (float*)p; p += 2048 * 4;                      // small fp32
    size_t need = (size_t)(p - (char*)d_ws);
    if (ws_size < need) {
        hipMemsetAsync(d_out, 0x41, (size_t)GN * 8 * 2, stream);  // marker 12.06
        return;
    }

    // packed-weight arena offsets (shorts): w1,w2,w3,lw1,lw2,lw3,lw4
    unsigned short* bp[7];
    int bpn[7] = {6144, 9216, 9216, 24576, 32768, 8192, 1024};
    {
        unsigned short* q = bpArena;
        for (int i = 0; i < 7; i++) { bp[i] = q; q += bpn[i]; }
    }

    // small fp32 arena: lb1(256),lb2(128),lb3(64),lb4(8), 6 x 96 scale/shift
    float* lb[4]; float* ss[6];
    {
        float* q = fArena;
        int ln[4] = {256, 128, 64, 8};
        for (int i = 0; i < 4; i++) { lb[i] = q; q += ln[i]; }
        for (int i = 0; i < 6; i++) { ss[i] = q; q += 96; }
    }

    const int* ei = (const int*)d_in[1];
    const unsigned short* xw = (const unsigned short*)d_in[0];

    // graph build + weight prep + X->bf16: memset, merged kernel, csr
    hipMemsetAsync(gcur, 0, NPART * 4, stream);
    {
        PackAll pa;
        int wsrc[7] = {2, 6, 10, 14, 16, 18, 20};
        int Ks[7] = {64, 96, 96, 96, 256, 128, 64};
        int Ms[7] = {96, 96, 96, 256, 128, 64, 8};
        int cum = 0;
        for (int i = 0; i < 7; i++) {
            pa.src[i] = d_in[wsrc[i]]; pa.dst[i] = bp[i];
            pa.K[i] = Ks[i]; pa.M[i] = Ms[i];
            pa.start[i] = cum;
            cum += (Ms[i] + 15) / 16 * (Ks[i] / 32);
        }
        pa.start[7] = cum;   // 178
        SmallCvt sc;
        int lsrc[4] = {15, 17, 19, 21};
        int ln[4] = {256, 128, 64, 8};
        for (int i = 0; i < 4; i++) { sc.src[i] = d_in[lsrc[i]]; sc.dst[i] = lb[i]; sc.n[i] = ln[i]; }
        int gsrc[9] = {3, 4, 5, 7, 8, 9, 11, 12, 13};
        for (int i = 0; i < 9; i++) sc.gb[i] = d_in[gsrc[i]];
        for (int i = 0; i < 6; i++) sc.ss[i] = ss[i];
        Arthur1_16458314678864_kernel<<<2000, 256, 0, stream>>>(
            pa, sc, ei, xw, flagI, flagF, gcur, pairs, xb, bufA, bufB, dinv);
    }
    ar1_csr<<<NPART, 256, 0, stream>>>(pairs, gcur, csr, indeg, offs, dinv, xb);

    const int FB = GN / 16;           // 3125 (fused kernels, 1024 thr)

    // GCN layers 1,2 fused agg+GEMM; layer 3 + GEMM3 + MLP in one kernel
    ar1_ag64g<<<FB, 1024, 0, stream>>>(xb, offs, indeg, csr, dinv,
                                       bp[0], ss[0], ss[1], bufA);
    ar1_ag96g<<<FB, 1024, 0, stream>>>(bufA, offs, indeg, csr, dinv,
                                       bp[1], ss[2], ss[3], bufB);
    ar1_agmlp<<<FB, 1024, 0, stream>>>(bufB, offs, indeg, csr, dinv,
                                       bp[2], ss[4], ss[5],
                                       bp[3], bp[4], bp[5], bp[6],
                                       lb[0], lb[1], lb[2], lb[3], d_out, flagF);
}